// Round 15
// baseline (263.130 us; speedup 1.0000x reference)
//
#include <hip/hip_runtime.h>
#include <hip/hip_bf16.h>

typedef __attribute__((ext_vector_type(8))) short bf16x8;    // 8 bf16 = 4 VGPR
typedef __attribute__((ext_vector_type(4))) short bf16x4;    // 4 bf16 = 2 VGPR
typedef __attribute__((ext_vector_type(4))) float f32x4;
typedef __attribute__((ext_vector_type(16))) float f32x16;

#define GLOBAL_AS __attribute__((address_space(1)))
#define LDS_AS __attribute__((address_space(3)))

static __device__ __forceinline__ void async16(void* lds, const void* g) {
  // 16B global -> LDS direct (wave-uniform LDS base + lane*16)
  __builtin_amdgcn_global_load_lds((const GLOBAL_AS void*)g, (LDS_AS void*)lds, 16, 0, 0);
}

static __device__ __forceinline__ short f2bf(float f) {  // RNE (manual, off hot path)
  union { float f; unsigned u; } v; v.f = f;
  unsigned r = v.u + 0x7fffu + ((v.u >> 16) & 1u);
  return (short)(r >> 16);
}

static __device__ __forceinline__ unsigned cvtpk(float lo, float hi) {  // 2xf32 -> 2xbf16 (RNE)
  unsigned r;
  asm("v_cvt_pk_bf16_f32 %0, %1, %2" : "=v"(r) : "v"(lo), "v"(hi));
  return r;
}

// bare v_exp_f32 via the COMPILER BUILTIN (hazard-aware). NOTE: raw inline-asm
// v_exp_f32 is WRONG — TRANS ops need a wait-state before the consumer, and the
// hazard recognizer can't see inside an asm block (R11 failure, absmax 4e4).
// Builtin vs OCML exp2f was worth 33 µs on this kernel (R12).
#define EXP2(x) __builtin_amdgcn_exp2f(x)

#define S_LEN 2048
#define D_MODEL 1024
#define H_DIM 64
#define M_TOT 8192
#define QSCALE 0.18033688011112042f   /* 0.125 * log2(e): scores in log2 domain */

// ---------------- convert weights fp32->bf16 + mask bit-pack ----------------
// q/k/v are no longer pre-converted: the GEMMs stage fp32 directly (A32/B32).
__global__ __launch_bounds__(256) void convert_pack(
    const float* __restrict__ wq, const float* __restrict__ wk, const float* __restrict__ wv,
    const float* __restrict__ wo, const int* __restrict__ mask,
    short* __restrict__ wqb, short* __restrict__ wkb, short* __restrict__ wvb,
    short* __restrict__ wob, unsigned long long* __restrict__ mbits)
{
  int bid = blockIdx.x;
  if (bid < 2048) {                      // 2048*256*8 = 4194304 = 4 x 1024^2 exactly
    long long e = ((long long)bid * 256 + threadIdx.x) * 8;
    const float* src; short* dst; long long off;
    if      (e < 1048576) { src = wq; dst = wqb; off = e; }
    else if (e < 2097152) { src = wk; dst = wkb; off = e - 1048576; }
    else if (e < 3145728) { src = wv; dst = wvb; off = e - 2097152; }
    else                  { src = wo; dst = wob; off = e - 3145728; }
    float4 f0 = *(const float4*)(src + off);
    float4 f1 = *(const float4*)(src + off + 4);
    bf16x8 r;
    r[0]=f2bf(f0.x); r[1]=f2bf(f0.y); r[2]=f2bf(f0.z); r[3]=f2bf(f0.w);
    r[4]=f2bf(f1.x); r[5]=f2bf(f1.y); r[6]=f2bf(f1.z); r[7]=f2bf(f1.w);
    *(bf16x8*)(dst + off) = r;
  } else {                               // mask: 2048 rows x 32 u64 words, 1 wave/word
    int wid = (bid - 2048) * 4 + (threadIdx.x >> 6);
    int lane = threadIdx.x & 63;
    int mv = mask[(long long)wid * 64 + lane];
    unsigned long long bal = __ballot(mv != 0);
    if (lane == 0) mbits[wid] = bal;
  }
}

// ---------------- bf16 GEMM, C[M,N] = A[M,K] * Bt[N,K]^T, (acc+bias)*scale ----------------
// A32/B32: that operand is fp32 in global; staged as fp32 (4-iter, ^(row&7)
// swizzle over 8 f32-chunks/row) and converted to bf16 fragments in-register
// (2x ds_read_b128 + 4x v_cvt_pk_bf16_f32 — same RNE as upfront convert).
// mode bits: 1 = bias indexed by row; 2 = permute C column (swap bits 2,3 of
// the within-16 index — V^T token permutation for attention).
struct GB { const short* A; const short* Bt; void* C; const float* bias; float scale; int N; int mode; };

template<int OUT_BF16, int A32, int B32>
__global__ __launch_bounds__(256) void gemm_bt(GB g0, GB g1, GB g2)
{
  GB g = (blockIdx.z == 0) ? g0 : ((blockIdx.z == 1) ? g1 : g2);
  const int K = 1024;
  const int N = g.N;
  __shared__ __align__(16) short As[128 * 32 * (A32 ? 2 : 1)];
  __shared__ __align__(16) short Bs[128 * 32 * (B32 ? 2 : 1)];
  int tid = threadIdx.x;
  int lane = tid & 63, wave = tid >> 6;
  int wr = wave >> 1, wc = wave & 1;
  long long m0 = (long long)blockIdx.y * 128;
  int n0 = blockIdx.x * 128;
  const short* Ab = g.A + (A32 ? 2 : 1) * m0 * K;           // bf16: +m0*K shorts; fp32: same bytes via 2x
  const short* Bb = g.Bt + (B32 ? 2 : 1) * (long long)n0 * K;

  f32x4 acc[4][4];
#pragma unroll
  for (int m = 0; m < 4; ++m)
#pragma unroll
    for (int n = 0; n < 4; ++n) { f32x4 z = {0.f,0.f,0.f,0.f}; acc[m][n] = z; }

  for (int k0 = 0; k0 < K; k0 += 32) {
    __syncthreads();                      // prev tile reads done
    if (A32) {                            // A tile 128x32 f32: 1024 16B slots
      const float* Af = (const float*)Ab;
#pragma unroll
      for (int it = 0; it < 4; ++it) {
        int f = it * 256 + tid;
        int row = f >> 3, cs = f & 7, c = cs ^ (row & 7);
        async16(&((float*)As)[(it * 256 + (tid & 192)) * 4],
                Af + (long long)row * K + k0 + c * 4);
      }
    } else {                              // A tile 128x32 bf16: 512 16B slots
#pragma unroll
      for (int it = 0; it < 2; ++it) {
        int f = it * 256 + tid;
        int row = f >> 2, cs = f & 3, c = cs ^ (row & 3);
        async16(&As[(it * 256 + (tid & 192)) * 8], Ab + (long long)row * K + k0 + c * 8);
      }
    }
    if (B32) {
      const float* Bf = (const float*)Bb;
#pragma unroll
      for (int it = 0; it < 4; ++it) {
        int f = it * 256 + tid;
        int row = f >> 3, cs = f & 7, c = cs ^ (row & 7);
        async16(&((float*)Bs)[(it * 256 + (tid & 192)) * 4],
                Bf + (long long)row * K + k0 + c * 4);
      }
    } else {
#pragma unroll
      for (int it = 0; it < 2; ++it) {
        int f = it * 256 + tid;
        int row = f >> 2, cs = f & 3, c = cs ^ (row & 3);
        async16(&Bs[(it * 256 + (tid & 192)) * 8], Bb + (long long)row * K + k0 + c * 8);
      }
    }
    __syncthreads();                      // staging visible (vmcnt drained)

    int gq = lane >> 4;
    bf16x8 af[4], bfr[4];
#pragma unroll
    for (int m = 0; m < 4; ++m) {
      int r = wr * 64 + m * 16 + (lane & 15);
      if (A32) {
        const float* Asf = (const float*)As;
        int c0 = (2 * gq) ^ (r & 7), c1 = (2 * gq + 1) ^ (r & 7);
        f32x4 v0 = *(const f32x4*)&Asf[(r * 8 + c0) * 4];
        f32x4 v1 = *(const f32x4*)&Asf[(r * 8 + c1) * 4];
        union { unsigned w[4]; bf16x8 v; } fu;
        fu.w[0] = cvtpk(v0[0], v0[1]); fu.w[1] = cvtpk(v0[2], v0[3]);
        fu.w[2] = cvtpk(v1[0], v1[1]); fu.w[3] = cvtpk(v1[2], v1[3]);
        af[m] = fu.v;
      } else {
        int cs = gq ^ (r & 3);
        af[m] = *(const bf16x8*)&As[r * 32 + cs * 8];
      }
    }
#pragma unroll
    for (int n = 0; n < 4; ++n) {
      int r = wc * 64 + n * 16 + (lane & 15);
      if (B32) {
        const float* Bsf = (const float*)Bs;
        int c0 = (2 * gq) ^ (r & 7), c1 = (2 * gq + 1) ^ (r & 7);
        f32x4 v0 = *(const f32x4*)&Bsf[(r * 8 + c0) * 4];
        f32x4 v1 = *(const f32x4*)&Bsf[(r * 8 + c1) * 4];
        union { unsigned w[4]; bf16x8 v; } fu;
        fu.w[0] = cvtpk(v0[0], v0[1]); fu.w[1] = cvtpk(v0[2], v0[3]);
        fu.w[2] = cvtpk(v1[0], v1[1]); fu.w[3] = cvtpk(v1[2], v1[3]);
        bfr[n] = fu.v;
      } else {
        int cs = gq ^ (r & 3);
        bfr[n] = *(const bf16x8*)&Bs[r * 32 + cs * 8];
      }
    }
#pragma unroll
    for (int m = 0; m < 4; ++m)
#pragma unroll
      for (int n = 0; n < 4; ++n)
        acc[m][n] = __builtin_amdgcn_mfma_f32_16x16x32_bf16(af[m], bfr[n], acc[m][n], 0, 0, 0);
  }

  // epilogue: C layout col = lane&15, row = (lane>>4)*4 + j  [m89/m91]
  int cc = lane & 15;
  if (g.mode & 2) cc = (cc & 3) | ((cc & 4) << 1) | ((cc & 8) >> 1);   // swap bits 2,3
  bool brow_mode = (g.mode & 1) != 0;
  float bcol[4];
  if (!brow_mode) {
#pragma unroll
    for (int n = 0; n < 4; ++n) bcol[n] = g.bias[n0 + wc * 64 + n * 16 + (lane & 15)];
  }
  long long crow0 = m0 + wr * 64 + ((lane >> 4) * 4);
  int ccol0 = n0 + wc * 64 + cc;
#pragma unroll
  for (int m = 0; m < 4; ++m) {
    float brow[4];
    if (brow_mode) {
#pragma unroll
      for (int j = 0; j < 4; ++j) brow[j] = g.bias[crow0 + m * 16 + j];
    }
#pragma unroll
    for (int n = 0; n < 4; ++n)
#pragma unroll
      for (int j = 0; j < 4; ++j) {
        long long row = crow0 + m * 16 + j;
        int col = ccol0 + n * 16;
        float val = (acc[m][n][j] + (brow_mode ? brow[j] : bcol[n])) * g.scale;
        if (OUT_BF16) ((short*)g.C)[row * N + col] = f2bf(val);
        else          ((float*)g.C)[row * N + col] = val;
      }
  }
}

// ---------------- flash attention, 32x32x16 MFMA, fixed-shift softmax ----------------
// R14 structure, UNCHANGED (99.3 µs best): 2 LDS buffers (32KB),
// __syncthreads-per-tile protocol, 84 VGPR + 32 acc = 116 regs.
// Softmax: fixed shift p = exp2(sc-4) (-4 in the QK^T MFMA C operand); row-sum
// via VALU pairwise tree into lrow, completed by one shfl_xor(32) at the end.
__global__ __launch_bounds__(256, 3) void attn_fwd(
    const short* __restrict__ Qb, const short* __restrict__ Kb, const short* __restrict__ Vtg,
    const unsigned long long* __restrict__ mbits, short* __restrict__ Xb)
{
  int bh = blockIdx.y;
  int b = bh >> 4, hh = bh & 15;
  int q0 = blockIdx.x * 128;
  int tid = threadIdx.x, lane = tid & 63, wave = tid >> 6;
  int ql = lane & 31, h = lane >> 5;
  const short* Qh = Qb + (long long)b * S_LEN * D_MODEL + hh * H_DIM;
  const short* Kh = Kb + (long long)b * S_LEN * D_MODEL + hh * H_DIM;
  const short* Vh = Vtg + (long long)(hh * H_DIM) * M_TOT + b * S_LEN;  // V^T rows = d

  __shared__ __align__(16) short Ks[2][64 * 64];   // K rows, chunk-swizzled ^(row&7)
  __shared__ __align__(16) short Vs[2][64 * 64];   // V^T rows (d), chunk-swizzled ^(d&7)

  int qr = q0 + wave * 32 + ql;
  bf16x8 qf[4];                            // Q[qr][dk*16 + 8h + 0..7]
#pragma unroll
  for (int dk = 0; dk < 4; ++dk)
    qf[dk] = *(const bf16x8*)&Qh[(long long)qr * D_MODEL + dk * 16 + h * 8];

  // ---- hoisted per-lane offsets (elements) ----
  const int fA = tid, fB = 256 + tid;
  const int rA = fA >> 3, rB = fB >> 3;
  const int swA = ((fA & 7) ^ (rA & 7)) * 8, swB = ((fB & 7) ^ (rB & 7)) * 8;
  const int kgA = rA * D_MODEL + swA, kgB = rB * D_MODEL + swB;   // K staging src
  const int vgA = rA * M_TOT + swA,  vgB = rB * M_TOT + swB;      // V staging src
  const int ldA = (tid & 192) * 8, ldB = (256 + (tid & 192)) * 8; // LDS dst

  int rdK[2][4];   // QK A-frag: row kt*32+ql, chunk (2dk+h)^(row&7)
#pragma unroll
  for (int kt = 0; kt < 2; ++kt)
#pragma unroll
    for (int dk = 0; dk < 4; ++dk)
      rdK[kt][dk] = (kt * 32 + ql) * 64 + (((2 * dk + h) ^ (lane & 7)) * 8);
  int rdV[2][4];   // PV A-frag: row dt*32+ql, chunk (2kt16+h)^(row&7)
#pragma unroll
  for (int dt = 0; dt < 2; ++dt)
#pragma unroll
    for (int kt16 = 0; kt16 < 4; ++kt16)
      rdV[dt][kt16] = (dt * 32 + ql) * 64 + (((2 * kt16 + h) ^ (lane & 7)) * 8);

  const unsigned long long* mpb = mbits + (long long)qr * 32;

  f32x16 accO[2], INIT;
#pragma unroll
  for (int r = 0; r < 16; ++r) { accO[0][r] = 0.f; accO[1][r] = 0.f; INIT[r] = -4.0f; }
  float lrow = 0.f;   // this lane's partial row sum (its 32 of the 64 k's per tile)

#define STAGE(t, BUF) do {                                                   \
    const short* Kt_ = Kh + (long long)(t) * (64 * D_MODEL);                 \
    async16(&Ks[BUF][ldA], Kt_ + kgA);                                       \
    async16(&Ks[BUF][ldB], Kt_ + kgB);                                       \
    const short* Vt_ = Vh + (t) * 64;                                        \
    async16(&Vs[BUF][ldA], Vt_ + vgA);                                       \
    async16(&Vs[BUF][ldB], Vt_ + vgB);                                       \
  } while (0)

#define TILE(t, CUR) do {                                                            \
    unsigned long long mw_next = ((t) < 31) ? mpb[(t) + 1] : 0ull;                   \
    if ((t) < 31) STAGE((t) + 1, 1 - (CUR));                                         \
    const short* ksb = &Ks[CUR][0];                                                  \
    const short* vsb = &Vs[CUR][0];                                                  \
    unsigned long long msh = mw >> (4 * h);                                          \
    bf16x8 pbf[4];                                                                   \
    _Pragma("unroll") for (int kt = 0; kt < 2; ++kt) {                               \
      bf16x8 kf0 = *(const bf16x8*)(ksb + rdK[kt][0]);                               \
      f32x16 s = __builtin_amdgcn_mfma_f32_32x32x16_bf16(kf0, qf[0], INIT, 0, 0, 0); \
      _Pragma("unroll") for (int dk = 1; dk < 4; ++dk) {                             \
        bf16x8 kf = *(const bf16x8*)(ksb + rdK[kt][dk]);                             \
        s = __builtin_amdgcn_mfma_f32_32x32x16_bf16(kf, qf[dk], s, 0, 0, 0);         \
      }                                                                              \
      unsigned mwd = kt ? (unsigned)(msh >> 32) : (unsigned)msh;                     \
      float pe[16];                                                                  \
      _Pragma("unroll") for (int r = 0; r < 16; ++r) {                               \
        float pv = EXP2(s[r]);                                                       \
        int sm = __builtin_amdgcn_sbfe(mwd, (r & 3) + 8 * (r >> 2), 1);              \
        union { float f; unsigned u; } pu; pu.f = pv;                                \
        pu.u &= (unsigned)sm;                                                        \
        pe[r] = pu.f;                                                                \
      }                                                                              \
      float s0_ = pe[0] + pe[1],   s1_ = pe[2] + pe[3];                              \
      float s2_ = pe[4] + pe[5],   s3_ = pe[6] + pe[7];                              \
      float s4_ = pe[8] + pe[9],   s5_ = pe[10] + pe[11];                            \
      float s6_ = pe[12] + pe[13], s7_ = pe[14] + pe[15];                            \
      lrow += ((s0_ + s1_) + (s2_ + s3_)) + ((s4_ + s5_) + (s6_ + s7_));             \
      union { unsigned w[4]; bf16x8 v; } b0, b1;                                     \
      b0.w[0] = cvtpk(pe[0], pe[1]);   b0.w[1] = cvtpk(pe[2], pe[3]);                \
      b0.w[2] = cvtpk(pe[4], pe[5]);   b0.w[3] = cvtpk(pe[6], pe[7]);                \
      b1.w[0] = cvtpk(pe[8], pe[9]);   b1.w[1] = cvtpk(pe[10], pe[11]);              \
      b1.w[2] = cvtpk(pe[12], pe[13]); b1.w[3] = cvtpk(pe[14], pe[15]);              \
      pbf[kt * 2] = b0.v; pbf[kt * 2 + 1] = b1.v;                                    \
    }                                                                                \
    __builtin_amdgcn_s_setprio(1);                                                   \
    _Pragma("unroll") for (int kt16 = 0; kt16 < 4; ++kt16) {                         \
      _Pragma("unroll") for (int dt = 0; dt < 2; ++dt) {                             \
        bf16x8 vf = *(const bf16x8*)(vsb + rdV[dt][kt16]);                           \
        accO[dt] = __builtin_amdgcn_mfma_f32_32x32x16_bf16(vf, pbf[kt16], accO[dt], 0, 0, 0); \
      }                                                                              \
    }                                                                                \
    __builtin_amdgcn_s_setprio(0);                                                   \
    mw = mw_next;                                                                    \
    __syncthreads();   /* drains vmcnt: tile t+1 staged; buf[CUR] reads done */      \
  } while (0)

  STAGE(0, 0);
  unsigned long long mw = mpb[0];
  __syncthreads();

  for (int t = 0; t < 32; t += 2) {
    TILE(t, 0);
    TILE(t + 1, 1);
  }

  // complete the row sum: partner lane (lane^32) holds the other 32 k-slots.
  lrow += __shfl_xor(lrow, 32);
  float inv = 1.0f / lrow;

  // epilogue: accO[dt][r] = O^T[d = dt*32+(r&3)+8*(r>>2)+4h][q = qr]
  short* xb = Xb + ((long long)b * S_LEN + qr) * D_MODEL + hh * H_DIM;
#pragma unroll
  for (int dt = 0; dt < 2; ++dt)
#pragma unroll
    for (int r0 = 0; r0 < 16; r0 += 4) {
      int d0 = dt * 32 + 8 * (r0 >> 2) + 4 * h;
      union { unsigned w[2]; bf16x4 v; } ob;
      ob.w[0] = cvtpk(accO[dt][r0 + 0] * inv, accO[dt][r0 + 1] * inv);
      ob.w[1] = cvtpk(accO[dt][r0 + 2] * inv, accO[dt][r0 + 3] * inv);
      *(bf16x4*)&xb[d0] = ob.v;
    }
#undef TILE
#undef STAGE
}

// ---------------- launch ----------------
extern "C" void kernel_launch(void* const* d_in, const int* in_sizes, int n_in,
                              void* d_out, int out_size, void* d_ws, size_t ws_size,
                              hipStream_t stream) {
  const float* q   = (const float*)d_in[0];
  const float* k   = (const float*)d_in[1];
  const float* v   = (const float*)d_in[2];
  const int*  mask = (const int*)d_in[3];
  const float* Wq  = (const float*)d_in[4];
  const float* bq  = (const float*)d_in[5];
  const float* Wk  = (const float*)d_in[6];
  const float* bk  = (const float*)d_in[7];
  const float* Wv  = (const float*)d_in[8];
  const float* bv  = (const float*)d_in[9];
  const float* Wo  = (const float*)d_in[10];
  const float* bo  = (const float*)d_in[11];

  char* w = (char*)d_ws;
  short* wqb = (short*)(w + 50331648LL);
  short* wkb = (short*)(w + 52428800LL);
  short* wvb = (short*)(w + 54525952LL);
  short* wob = (short*)(w + 56623104LL);
  short* Qb  = (short*)(w + 58720256LL);
  short* Kb  = (short*)(w + 75497472LL);
  short* Vtg = (short*)(w + 92274688LL);   // V^T: [1024 d][8192 tokens, bits2<->3 permuted]
  short* Xb  = (short*)(w + 109051904LL);
  unsigned long long* mbits = (unsigned long long*)(w + 125829120LL);
  // total ws use: 126353408 bytes

  // weights + mask only (q/k/v staged as fp32 directly by the GEMMs)
  convert_pack<<<18432, 256, 0, stream>>>(Wq, Wk, Wv, Wo, mask,
                                          wqb, wkb, wvb, wob, mbits);
  // Q,K projections: A = fp32 activations, B = bf16 weights. Q folds (1/8)*log2(e).
  GB gq{(const short*)q, wqb, (void*)Qb, bq, QSCALE, 1024, 0};
  GB gk{(const short*)k, wkb, (void*)Kb, bk, 1.0f, 1024, 0};
  gemm_bt<1, 1, 0><<<dim3(8, 64, 2), 256, 0, stream>>>(gq, gk, gk);
  // V projection TRANSPOSED: A = Wv (bf16), B = v (fp32); row-bias + token perm.
  GB gv{wvb, (const short*)v, (void*)Vtg, bv, 1.0f, 8192, 1 | 2};
  gemm_bt<1, 0, 1><<<dim3(64, 8, 1), 256, 0, stream>>>(gv, gv, gv);

  attn_fwd<<<dim3(16, 64), 256, 0, stream>>>(Qb, Kb, Vtg, mbits, Xb);

  GB go{Xb, wob, d_out, bo, 1.0f, 1024, 0};
  gemm_bt<0, 0, 0><<<dim3(8, 64, 1), 256, 0, stream>>>(go, go, go);
}

// Round 16
// 221.457 us; speedup vs baseline: 1.1882x; 1.1882x over previous
//
#include <hip/hip_runtime.h>
#include <hip/hip_bf16.h>

typedef __attribute__((ext_vector_type(8))) short bf16x8;    // 8 bf16 = 4 VGPR
typedef __attribute__((ext_vector_type(4))) short bf16x4;    // 4 bf16 = 2 VGPR
typedef __attribute__((ext_vector_type(4))) float f32x4;
typedef __attribute__((ext_vector_type(16))) float f32x16;

#define GLOBAL_AS __attribute__((address_space(1)))
#define LDS_AS __attribute__((address_space(3)))

static __device__ __forceinline__ void async16(void* lds, const void* g) {
  // 16B global -> LDS direct (wave-uniform LDS base + lane*16)
  __builtin_amdgcn_global_load_lds((const GLOBAL_AS void*)g, (LDS_AS void*)lds, 16, 0, 0);
}

static __device__ __forceinline__ short f2bf(float f) {  // RNE (manual, off hot path)
  union { float f; unsigned u; } v; v.f = f;
  unsigned r = v.u + 0x7fffu + ((v.u >> 16) & 1u);
  return (short)(r >> 16);
}

static __device__ __forceinline__ unsigned cvtpk(float lo, float hi) {  // 2xf32 -> 2xbf16 (RNE)
  unsigned r;
  asm("v_cvt_pk_bf16_f32 %0, %1, %2" : "=v"(r) : "v"(lo), "v"(hi));
  return r;
}

// bare v_exp_f32 via the COMPILER BUILTIN (hazard-aware). NOTE: raw inline-asm
// v_exp_f32 is WRONG — TRANS ops need a wait-state before the consumer (R11).
#define EXP2(x) __builtin_amdgcn_exp2f(x)

#define S_LEN 2048
#define D_MODEL 1024
#define H_DIM 64
#define M_TOT 8192
#define QSCALE 0.18033688011112042f   /* 0.125 * log2(e): scores in log2 domain */

// ---------------- convert fp32->bf16 + mask bit-pack ----------------
__global__ __launch_bounds__(256) void convert_pack(
    const float* __restrict__ q, const float* __restrict__ k, const float* __restrict__ v,
    const float* __restrict__ wq, const float* __restrict__ wk, const float* __restrict__ wv,
    const float* __restrict__ wo, const int* __restrict__ mask,
    short* __restrict__ qb, short* __restrict__ kb, short* __restrict__ vb,
    short* __restrict__ wqb, short* __restrict__ wkb, short* __restrict__ wvb,
    short* __restrict__ wob, unsigned long long* __restrict__ mbits)
{
  int bid = blockIdx.x;
  if (bid < 14336) {                     // 14336*256*8 = 29360128 bf16 elems exactly
    long long e = ((long long)bid * 256 + threadIdx.x) * 8;
    const float* src; short* dst; long long off;
    if      (e < 8388608)  { src = q;  dst = qb;  off = e; }
    else if (e < 16777216) { src = k;  dst = kb;  off = e - 8388608; }
    else if (e < 25165824) { src = v;  dst = vb;  off = e - 16777216; }
    else if (e < 26214400) { src = wq; dst = wqb; off = e - 25165824; }
    else if (e < 27262976) { src = wk; dst = wkb; off = e - 26214400; }
    else if (e < 28311552) { src = wv; dst = wvb; off = e - 27262976; }
    else                   { src = wo; dst = wob; off = e - 28311552; }
    float4 f0 = *(const float4*)(src + off);
    float4 f1 = *(const float4*)(src + off + 4);
    bf16x8 r;
    r[0]=f2bf(f0.x); r[1]=f2bf(f0.y); r[2]=f2bf(f0.z); r[3]=f2bf(f0.w);
    r[4]=f2bf(f1.x); r[5]=f2bf(f1.y); r[6]=f2bf(f1.z); r[7]=f2bf(f1.w);
    *(bf16x8*)(dst + off) = r;
  } else {                               // mask: 2048 rows x 32 u64 words, 1 wave/word
    int wid = (bid - 14336) * 4 + (threadIdx.x >> 6);
    int lane = threadIdx.x & 63;
    int mv = mask[(long long)wid * 64 + lane];
    unsigned long long bal = __ballot(mv != 0);
    if (lane == 0) mbits[wid] = bal;
  }
}

// ---------------- bf16 GEMM, C[M,N] = A[M,K] * Bt[N,K]^T, (acc+bias)*scale ----------------
// mode bits: 1 = bias indexed by row; 2 = permute C column (swap bits 2,3 of the
// within-16 index — V^T token permutation); 4 = transposed 64x8 grid (V slice).
// XCD-aware swizzle (T1): XCD = (x + 8y) % 8 (z*512 preserves phase). Decompose
// orig = 64a + 8b + xcd; each XCD gets 8 contiguous row-panels (A 2MB, L2-fit)
// x all col-blocks (B 2MB, L2-fit) -> per-XCD HBM ~4MB vs whole-A streaming.
struct GB { const short* A; const short* Bt; void* C; const float* bias; float scale; int N; int mode; };

template<int OUT_BF16>
__global__ __launch_bounds__(256) void gemm_bt(GB g0, GB g1, GB g2)
{
  GB g = (blockIdx.z == 0) ? g0 : ((blockIdx.z == 1) ? g1 : g2);
  const int K = 1024;
  const int N = g.N;
  __shared__ __align__(16) short As[128 * 32];
  __shared__ __align__(16) short Bs[128 * 32];
  int tid = threadIdx.x;
  int lane = tid & 63, wave = tid >> 6;
  int wr = wave >> 1, wc = wave & 1;
  int orig = blockIdx.x + (blockIdx.y << 3);          // 0..511
  int xcd = orig & 7, b8 = (orig >> 3) & 7, a = orig >> 6;
  int bx, by;
  if (g.mode & 4) { bx = xcd * 8 + b8; by = a; }      // V: 64 token-cols x 8 Wv panels
  else            { bx = a; by = xcd * 8 + b8; }      // normal: 8 cols x 64 row panels
  long long m0 = (long long)by * 128;
  int n0 = bx * 128;
  const short* Ab = g.A + m0 * K;
  const short* Bb = g.Bt + (long long)n0 * K;

  f32x4 acc[4][4];
#pragma unroll
  for (int m = 0; m < 4; ++m)
#pragma unroll
    for (int n = 0; n < 4; ++n) { f32x4 z = {0.f,0.f,0.f,0.f}; acc[m][n] = z; }

  for (int k0 = 0; k0 < K; k0 += 32) {
    __syncthreads();                      // prev tile reads done
#pragma unroll
    for (int it = 0; it < 2; ++it) {      // A tile 128x32: 512 16B slots
      int f = it * 256 + tid;
      int row = f >> 2, cs = f & 3, c = cs ^ (row & 3);
      async16(&As[(it * 256 + (tid & 192)) * 8], Ab + (long long)row * K + k0 + c * 8);
    }
#pragma unroll
    for (int it = 0; it < 2; ++it) {
      int f = it * 256 + tid;
      int row = f >> 2, cs = f & 3, c = cs ^ (row & 3);
      async16(&Bs[(it * 256 + (tid & 192)) * 8], Bb + (long long)row * K + k0 + c * 8);
    }
    __syncthreads();                      // staging visible (vmcnt drained)

    bf16x8 af[4], bfr[4];
#pragma unroll
    for (int m = 0; m < 4; ++m) {
      int r = wr * 64 + m * 16 + (lane & 15);
      int cs = (lane >> 4) ^ (r & 3);
      af[m] = *(const bf16x8*)&As[r * 32 + cs * 8];
    }
#pragma unroll
    for (int n = 0; n < 4; ++n) {
      int r = wc * 64 + n * 16 + (lane & 15);
      int cs = (lane >> 4) ^ (r & 3);
      bfr[n] = *(const bf16x8*)&Bs[r * 32 + cs * 8];
    }
#pragma unroll
    for (int m = 0; m < 4; ++m)
#pragma unroll
      for (int n = 0; n < 4; ++n)
        acc[m][n] = __builtin_amdgcn_mfma_f32_16x16x32_bf16(af[m], bfr[n], acc[m][n], 0, 0, 0);
  }

  // epilogue: C layout col = lane&15, row = (lane>>4)*4 + j  [m89/m91]
  int cc = lane & 15;
  if (g.mode & 2) cc = (cc & 3) | ((cc & 4) << 1) | ((cc & 8) >> 1);   // swap bits 2,3
  bool brow_mode = (g.mode & 1) != 0;
  float bcol[4];
  if (!brow_mode) {
#pragma unroll
    for (int n = 0; n < 4; ++n) bcol[n] = g.bias[n0 + wc * 64 + n * 16 + (lane & 15)];
  }
  long long crow0 = m0 + wr * 64 + ((lane >> 4) * 4);
  int ccol0 = n0 + wc * 64 + cc;
#pragma unroll
  for (int m = 0; m < 4; ++m) {
    float brow[4];
    if (brow_mode) {
#pragma unroll
      for (int j = 0; j < 4; ++j) brow[j] = g.bias[crow0 + m * 16 + j];
    }
#pragma unroll
    for (int n = 0; n < 4; ++n)
#pragma unroll
      for (int j = 0; j < 4; ++j) {
        long long row = crow0 + m * 16 + j;
        int col = ccol0 + n * 16;
        float val = (acc[m][n][j] + (brow_mode ? brow[j] : bcol[n])) * g.scale;
        if (OUT_BF16) ((short*)g.C)[row * N + col] = f2bf(val);
        else          ((float*)g.C)[row * N + col] = val;
      }
  }
}

// ---------------- flash attention, 32x32x16 MFMA, fixed-shift softmax ----------------
// R14 structure (99.3 µs best): 2 LDS buffers (32KB), __syncthreads-per-tile,
// 84 VGPR + 32 acc = 116 regs. XCD swizzle added: XCD = (x + 16y) % 8; remap so
// each XCD owns 8 consecutive bh heads (their 16 q-blocks co-resident -> K/V
// tiles shared through the XCD's own L2 instead of L3).
// Softmax: fixed shift p = exp2(sc-4) (-4 in the QK^T MFMA C operand); row-sum
// via VALU pairwise tree into lrow, completed by one shfl_xor(32) at the end.
__global__ __launch_bounds__(256, 3) void attn_fwd(
    const short* __restrict__ Qb, const short* __restrict__ Kb, const short* __restrict__ Vtg,
    const unsigned long long* __restrict__ mbits, short* __restrict__ Xb)
{
  int orig = blockIdx.x + (blockIdx.y << 4);          // 0..1023
  int xcd = orig & 7, b8 = (orig >> 3) & 7, a = orig >> 6;   // a in 0..15
  int bh = xcd * 8 + b8;                              // 8 heads per XCD
  int b = bh >> 4, hh = bh & 15;
  int q0 = a * 128;
  int tid = threadIdx.x, lane = tid & 63, wave = tid >> 6;
  int ql = lane & 31, h = lane >> 5;
  const short* Qh = Qb + (long long)b * S_LEN * D_MODEL + hh * H_DIM;
  const short* Kh = Kb + (long long)b * S_LEN * D_MODEL + hh * H_DIM;
  const short* Vh = Vtg + (long long)(hh * H_DIM) * M_TOT + b * S_LEN;  // V^T rows = d

  __shared__ __align__(16) short Ks[2][64 * 64];   // K rows, chunk-swizzled ^(row&7)
  __shared__ __align__(16) short Vs[2][64 * 64];   // V^T rows (d), chunk-swizzled ^(d&7)

  int qr = q0 + wave * 32 + ql;
  bf16x8 qf[4];                            // Q[qr][dk*16 + 8h + 0..7]
#pragma unroll
  for (int dk = 0; dk < 4; ++dk)
    qf[dk] = *(const bf16x8*)&Qh[(long long)qr * D_MODEL + dk * 16 + h * 8];

  // ---- hoisted per-lane offsets (elements) ----
  const int fA = tid, fB = 256 + tid;
  const int rA = fA >> 3, rB = fB >> 3;
  const int swA = ((fA & 7) ^ (rA & 7)) * 8, swB = ((fB & 7) ^ (rB & 7)) * 8;
  const int kgA = rA * D_MODEL + swA, kgB = rB * D_MODEL + swB;   // K staging src
  const int vgA = rA * M_TOT + swA,  vgB = rB * M_TOT + swB;      // V staging src
  const int ldA = (tid & 192) * 8, ldB = (256 + (tid & 192)) * 8; // LDS dst

  int rdK[2][4];   // QK A-frag: row kt*32+ql, chunk (2dk+h)^(row&7)
#pragma unroll
  for (int kt = 0; kt < 2; ++kt)
#pragma unroll
    for (int dk = 0; dk < 4; ++dk)
      rdK[kt][dk] = (kt * 32 + ql) * 64 + (((2 * dk + h) ^ (lane & 7)) * 8);
  int rdV[2][4];   // PV A-frag: row dt*32+ql, chunk (2kt16+h)^(row&7)
#pragma unroll
  for (int dt = 0; dt < 2; ++dt)
#pragma unroll
    for (int kt16 = 0; kt16 < 4; ++kt16)
      rdV[dt][kt16] = (dt * 32 + ql) * 64 + (((2 * kt16 + h) ^ (lane & 7)) * 8);

  const unsigned long long* mpb = mbits + (long long)qr * 32;

  f32x16 accO[2], INIT;
#pragma unroll
  for (int r = 0; r < 16; ++r) { accO[0][r] = 0.f; accO[1][r] = 0.f; INIT[r] = -4.0f; }
  float lrow = 0.f;   // this lane's partial row sum (its 32 of the 64 k's per tile)

#define STAGE(t, BUF) do {                                                   \
    const short* Kt_ = Kh + (long long)(t) * (64 * D_MODEL);                 \
    async16(&Ks[BUF][ldA], Kt_ + kgA);                                       \
    async16(&Ks[BUF][ldB], Kt_ + kgB);                                       \
    const short* Vt_ = Vh + (t) * 64;                                        \
    async16(&Vs[BUF][ldA], Vt_ + vgA);                                       \
    async16(&Vs[BUF][ldB], Vt_ + vgB);                                       \
  } while (0)

#define TILE(t, CUR) do {                                                            \
    unsigned long long mw_next = ((t) < 31) ? mpb[(t) + 1] : 0ull;                   \
    if ((t) < 31) STAGE((t) + 1, 1 - (CUR));                                         \
    const short* ksb = &Ks[CUR][0];                                                  \
    const short* vsb = &Vs[CUR][0];                                                  \
    unsigned long long msh = mw >> (4 * h);                                          \
    bf16x8 pbf[4];                                                                   \
    _Pragma("unroll") for (int kt = 0; kt < 2; ++kt) {                               \
      bf16x8 kf0 = *(const bf16x8*)(ksb + rdK[kt][0]);                               \
      f32x16 s = __builtin_amdgcn_mfma_f32_32x32x16_bf16(kf0, qf[0], INIT, 0, 0, 0); \
      _Pragma("unroll") for (int dk = 1; dk < 4; ++dk) {                             \
        bf16x8 kf = *(const bf16x8*)(ksb + rdK[kt][dk]);                             \
        s = __builtin_amdgcn_mfma_f32_32x32x16_bf16(kf, qf[dk], s, 0, 0, 0);         \
      }                                                                              \
      unsigned mwd = kt ? (unsigned)(msh >> 32) : (unsigned)msh;                     \
      float pe[16];                                                                  \
      _Pragma("unroll") for (int r = 0; r < 16; ++r) {                               \
        float pv = EXP2(s[r]);                                                       \
        int sm = __builtin_amdgcn_sbfe(mwd, (r & 3) + 8 * (r >> 2), 1);              \
        union { float f; unsigned u; } pu; pu.f = pv;                                \
        pu.u &= (unsigned)sm;                                                        \
        pe[r] = pu.f;                                                                \
      }                                                                              \
      float s0_ = pe[0] + pe[1],   s1_ = pe[2] + pe[3];                              \
      float s2_ = pe[4] + pe[5],   s3_ = pe[6] + pe[7];                              \
      float s4_ = pe[8] + pe[9],   s5_ = pe[10] + pe[11];                            \
      float s6_ = pe[12] + pe[13], s7_ = pe[14] + pe[15];                            \
      lrow += ((s0_ + s1_) + (s2_ + s3_)) + ((s4_ + s5_) + (s6_ + s7_));             \
      union { unsigned w[4]; bf16x8 v; } b0, b1;                                     \
      b0.w[0] = cvtpk(pe[0], pe[1]);   b0.w[1] = cvtpk(pe[2], pe[3]);                \
      b0.w[2] = cvtpk(pe[4], pe[5]);   b0.w[3] = cvtpk(pe[6], pe[7]);                \
      b1.w[0] = cvtpk(pe[8], pe[9]);   b1.w[1] = cvtpk(pe[10], pe[11]);              \
      b1.w[2] = cvtpk(pe[12], pe[13]); b1.w[3] = cvtpk(pe[14], pe[15]);              \
      pbf[kt * 2] = b0.v; pbf[kt * 2 + 1] = b1.v;                                    \
    }                                                                                \
    __builtin_amdgcn_s_setprio(1);                                                   \
    _Pragma("unroll") for (int kt16 = 0; kt16 < 4; ++kt16) {                         \
      _Pragma("unroll") for (int dt = 0; dt < 2; ++dt) {                             \
        bf16x8 vf = *(const bf16x8*)(vsb + rdV[dt][kt16]);                           \
        accO[dt] = __builtin_amdgcn_mfma_f32_32x32x16_bf16(vf, pbf[kt16], accO[dt], 0, 0, 0); \
      }                                                                              \
    }                                                                                \
    __builtin_amdgcn_s_setprio(0);                                                   \
    mw = mw_next;                                                                    \
    __syncthreads();   /* drains vmcnt: tile t+1 staged; buf[CUR] reads done */      \
  } while (0)

  STAGE(0, 0);
  unsigned long long mw = mpb[0];
  __syncthreads();

  for (int t = 0; t < 32; t += 2) {
    TILE(t, 0);
    TILE(t + 1, 1);
  }

  // complete the row sum: partner lane (lane^32) holds the other 32 k-slots.
  lrow += __shfl_xor(lrow, 32);
  float inv = 1.0f / lrow;

  // epilogue: accO[dt][r] = O^T[d = dt*32+(r&3)+8*(r>>2)+4h][q = qr]
  short* xb = Xb + ((long long)b * S_LEN + qr) * D_MODEL + hh * H_DIM;
#pragma unroll
  for (int dt = 0; dt < 2; ++dt)
#pragma unroll
    for (int r0 = 0; r0 < 16; r0 += 4) {
      int d0 = dt * 32 + 8 * (r0 >> 2) + 4 * h;
      union { unsigned w[2]; bf16x4 v; } ob;
      ob.w[0] = cvtpk(accO[dt][r0 + 0] * inv, accO[dt][r0 + 1] * inv);
      ob.w[1] = cvtpk(accO[dt][r0 + 2] * inv, accO[dt][r0 + 3] * inv);
      *(bf16x4*)&xb[d0] = ob.v;
    }
#undef TILE
#undef STAGE
}

// ---------------- launch ----------------
extern "C" void kernel_launch(void* const* d_in, const int* in_sizes, int n_in,
                              void* d_out, int out_size, void* d_ws, size_t ws_size,
                              hipStream_t stream) {
  const float* q   = (const float*)d_in[0];
  const float* k   = (const float*)d_in[1];
  const float* v   = (const float*)d_in[2];
  const int*  mask = (const int*)d_in[3];
  const float* Wq  = (const float*)d_in[4];
  const float* bq  = (const float*)d_in[5];
  const float* Wk  = (const float*)d_in[6];
  const float* bk  = (const float*)d_in[7];
  const float* Wv  = (const float*)d_in[8];
  const float* bv  = (const float*)d_in[9];
  const float* Wo  = (const float*)d_in[10];
  const float* bo  = (const float*)d_in[11];

  char* w = (char*)d_ws;
  short* qb  = (short*)(w + 0LL);
  short* kb  = (short*)(w + 16777216LL);
  short* vb  = (short*)(w + 33554432LL);
  short* wqb = (short*)(w + 50331648LL);
  short* wkb = (short*)(w + 52428800LL);
  short* wvb = (short*)(w + 54525952LL);
  short* wob = (short*)(w + 56623104LL);
  short* Qb  = (short*)(w + 58720256LL);
  short* Kb  = (short*)(w + 75497472LL);
  short* Vtg = (short*)(w + 92274688LL);   // V^T: [1024 d][8192 tokens, bits2<->3 permuted]
  short* Xb  = (short*)(w + 109051904LL);
  unsigned long long* mbits = (unsigned long long*)(w + 125829120LL);
  // total ws use: 126353408 bytes

  convert_pack<<<30720, 256, 0, stream>>>(q, k, v, Wq, Wk, Wv, Wo, mask,
                                          qb, kb, vb, wqb, wkb, wvb, wob, mbits);
  // Q,K,V projections in ONE dispatch. Q folds (1/8)*log2(e).
  // V slice: transposed grid (mode 4), row-bias (1), token perm (2).
  GB gq{qb, wqb, (void*)Qb, bq, QSCALE, 1024, 0};
  GB gk{kb, wkb, (void*)Kb, bk, 1.0f, 1024, 0};
  GB gv{wvb, vb, (void*)Vtg, bv, 1.0f, 8192, 1 | 2 | 4};
  gemm_bt<1><<<dim3(8, 64, 3), 256, 0, stream>>>(gq, gk, gv);

  attn_fwd<<<dim3(16, 64), 256, 0, stream>>>(Qb, Kb, Vtg, mbits, Xb);

  GB go{Xb, wob, d_out, bo, 1.0f, 1024, 0};
  gemm_bt<0><<<dim3(8, 64, 1), 256, 0, stream>>>(go, go, go);
}